// Round 7
// baseline (664.316 us; speedup 1.0000x reference)
//
#include <hip/hip_runtime.h>
#include <math.h>

#define B   128
#define IN  64
#define HS  500
#define OUT 10

typedef float f4 __attribute__((ext_vector_type(4)));

// ---------------------------------------------------------------------------
// Kernel 1: hactiv = tanh(i2h(x) + (w + alpha*pw) @ hidden)
// grid: B * (HS/4) blocks, 256 threads (4 waves; one output row i per wave)
// float4-vectorized: row stride = 500 floats = 2000 B (16B aligned)
// ---------------------------------------------------------------------------
__global__ __launch_bounds__(256)
void k_hactiv(const float* __restrict__ inputs,   // [B,IN]
              const float* __restrict__ hidden,   // [B,HS]
              const float* __restrict__ pw,       // [B,HS,HS]
              const float* __restrict__ i2h_w,    // [HS,IN]
              const float* __restrict__ i2h_b,    // [HS]
              const float* __restrict__ w,        // [HS,HS]
              const float* __restrict__ alpha,    // [HS,HS]
              float* __restrict__ hactiv,         // ws   [B,HS]
              float* __restrict__ hidden_new)     // d_out slot [B,HS]
{
    __shared__ f4 h_lds[HS / 4];                  // 125 vec4
    const int b    = blockIdx.x / (HS / 4);
    const int tile = blockIdx.x % (HS / 4);
    const int lane = threadIdx.x & 63;
    const int wv   = threadIdx.x >> 6;
    const int i    = tile * 4 + wv;

    if (threadIdx.x < HS / 4)
        h_lds[threadIdx.x] = ((const f4*)(hidden + (size_t)b * HS))[threadIdx.x];
    __syncthreads();

    const f4* __restrict__ pwrow = (const f4*)(pw + ((size_t)b * HS + i) * HS);
    const f4* __restrict__ wrow  = (const f4*)(w + (size_t)i * HS);
    const f4* __restrict__ arow  = (const f4*)(alpha + (size_t)i * HS);

    float acc = 0.f;
    #pragma unroll 2
    for (int v = lane; v < HS / 4; v += 64) {
        const f4 pv  = pwrow[v];
        const f4 wv4 = wrow[v];
        const f4 av  = arow[v];
        const f4 hv  = h_lds[v];
        acc += (wv4.x + av.x * pv.x) * hv.x
             + (wv4.y + av.y * pv.y) * hv.y
             + (wv4.z + av.z * pv.z) * hv.z
             + (wv4.w + av.w * pv.w) * hv.w;
    }

    // input projection: IN == 64, exactly one element per lane
    acc += inputs[b * IN + lane] * i2h_w[i * IN + lane];

    // wave64 shuffle reduce
    #pragma unroll
    for (int off = 32; off > 0; off >>= 1)
        acc += __shfl_down(acc, off, 64);

    if (lane == 0) {
        float v = tanhf(acc + i2h_b[i]);
        hactiv[b * HS + i]     = v;
        hidden_new[b * HS + i] = v;
    }
}

// ---------------------------------------------------------------------------
// Kernel 2: heads — activout [B,10], valueout [B,1], DAout [B] (tanh)
// grid: B blocks, 256 threads (4 waves × 3 outputs each = 12 outputs)
// ---------------------------------------------------------------------------
__global__ __launch_bounds__(256)
void k_heads(const float* __restrict__ hactiv,   // [B,HS]
             const float* __restrict__ h2o_w,    // [OUT,HS]
             const float* __restrict__ h2o_b,    // [OUT]
             const float* __restrict__ h2v_w,    // [1,HS]
             const float* __restrict__ h2v_b,    // [1]
             const float* __restrict__ h2DA_w,   // [1,HS]
             const float* __restrict__ h2DA_b,   // [1]
             float* __restrict__ activout,       // d_out [B,OUT]
             float* __restrict__ valueout,       // d_out [B]
             float* __restrict__ DAout)          // ws [B]
{
    __shared__ float h_lds[HS];
    const int b    = blockIdx.x;
    const int lane = threadIdx.x & 63;
    const int wv   = threadIdx.x >> 6;

    for (int j = threadIdx.x; j < HS; j += 256) h_lds[j] = hactiv[b * HS + j];
    __syncthreads();

    float acc[3] = {0.f, 0.f, 0.f};
    #pragma unroll
    for (int oo = 0; oo < 3; ++oo) {
        const int o = wv * 3 + oo;
        const float* __restrict__ wr =
            (o < OUT) ? (h2o_w + (size_t)o * HS) : ((o == OUT) ? h2v_w : h2DA_w);
        float a = 0.f;
        for (int j = lane; j < HS; j += 64) a += wr[j] * h_lds[j];
        acc[oo] = a;
    }
    #pragma unroll
    for (int off = 32; off > 0; off >>= 1) {
        #pragma unroll
        for (int oo = 0; oo < 3; ++oo)
            acc[oo] += __shfl_down(acc[oo], off, 64);
    }
    if (lane == 0) {
        #pragma unroll
        for (int oo = 0; oo < 3; ++oo) {
            const int o = wv * 3 + oo;
            if (o < OUT)          activout[b * OUT + o] = acc[oo] + h2o_b[o];
            else if (o == OUT)    valueout[b]           = acc[oo] + h2v_b[0];
            else                  DAout[b]              = tanhf(acc[oo] + h2DA_b[0]);
        }
    }
}

// ---------------------------------------------------------------------------
// Kernel 3: streaming trace update over [B,HS,HS] (float4, nontemporal)
//   hebb_new = hebb (copy; nt load + nt store — touched exactly once)
//   et_new   = (1-etaet)*et + etaet * hactiv_i * hidden_j   (nt load/store)
//   pw_new   = clip(pw + DAout_b * et, -1, 1)
//   pw load is NORMAL (not nt): phase 1 warmed pw into the 256 MB L3;
//   nt on everything else keeps L3 from evicting it before the re-read.
// grid: (32, B) blocks × 256 thr; grid-stride over 62500 vec4 per batch.
// b is block-uniform -> da/etaet/base are scalar; ~7.6 iters/thread of ILP.
// ---------------------------------------------------------------------------
#define NV4 (HS * HS / 4)   // 62500 vec4 per batch

__global__ __launch_bounds__(256)
void k_update(const f4* __restrict__ hebb,
              const f4* __restrict__ et,
              const f4* __restrict__ pw,
              const float* __restrict__ hactiv,   // [B,HS]
              const float* __restrict__ hidden,   // [B,HS] (old hidden)
              const float* __restrict__ DAout,    // [B]
              const float* __restrict__ etaet_p,  // [1]
              f4* __restrict__ hebb_new,
              f4* __restrict__ et_new,
              f4* __restrict__ pw_new)
{
    const int   b     = blockIdx.y;
    const float etaet = etaet_p[0];
    const float omete = 1.f - etaet;
    const float da    = DAout[b];
    const size_t base = (size_t)b * NV4;

    const float* __restrict__ harow = hactiv + (size_t)b * HS;
    const f4*    __restrict__ hrow  = (const f4*)(hidden + (size_t)b * HS);

    const int stride = gridDim.x * blockDim.x;          // 32*256 = 8192
    for (int v = blockIdx.x * blockDim.x + threadIdx.x; v < NV4; v += stride) {
        const int i  = v / (HS / 4);                    // magic-mul by 125
        const int j4 = v - i * (HS / 4);

        const float ha = harow[i] * etaet;              // L1/L2 hit
        const f4 hj = hrow[j4];                         // L1/L2 hit
        const f4 e  = __builtin_nontemporal_load(et + base + v);
        const f4 p  = pw[base + v];                     // hope: L3 hit
        const f4 hb = __builtin_nontemporal_load(hebb + base + v);

        f4 en, pn;
        en.x = omete * e.x + ha * hj.x;
        en.y = omete * e.y + ha * hj.y;
        en.z = omete * e.z + ha * hj.z;
        en.w = omete * e.w + ha * hj.w;

        pn.x = fminf(fmaxf(p.x + da * e.x, -1.f), 1.f);
        pn.y = fminf(fmaxf(p.y + da * e.y, -1.f), 1.f);
        pn.z = fminf(fmaxf(p.z + da * e.z, -1.f), 1.f);
        pn.w = fminf(fmaxf(p.w + da * e.w, -1.f), 1.f);

        __builtin_nontemporal_store(hb, hebb_new + base + v);
        __builtin_nontemporal_store(en, et_new + base + v);
        __builtin_nontemporal_store(pn, pw_new + base + v);
    }
}

// ---------------------------------------------------------------------------
extern "C" void kernel_launch(void* const* d_in, const int* in_sizes, int n_in,
                              void* d_out, int out_size, void* d_ws, size_t ws_size,
                              hipStream_t stream) {
    const float* inputs  = (const float*)d_in[0];
    const float* hidden  = (const float*)d_in[1];
    const float* hebb    = (const float*)d_in[2];
    const float* et      = (const float*)d_in[3];
    const float* pw      = (const float*)d_in[4];
    const float* i2h_w   = (const float*)d_in[5];
    const float* i2h_b   = (const float*)d_in[6];
    const float* w       = (const float*)d_in[7];
    const float* alpha   = (const float*)d_in[8];
    // d_in[9] = eta (unused in fully_modulated path)
    const float* etaet   = (const float*)d_in[10];
    const float* h2DA_w  = (const float*)d_in[11];
    const float* h2DA_b  = (const float*)d_in[12];
    const float* h2o_w   = (const float*)d_in[13];
    const float* h2o_b   = (const float*)d_in[14];
    const float* h2v_w   = (const float*)d_in[15];
    const float* h2v_b   = (const float*)d_in[16];

    float* out = (float*)d_out;
    // d_out layout (floats): activout[1280] | valueout[128] | hidden_new[64000]
    //                        | hebb_new[32M] | et_new[32M] | pw_new[32M]
    float* activout   = out;
    float* valueout   = out + B * OUT;                       // 1280
    float* hidden_new = out + B * OUT + B;                   // 1408
    float* hebb_new   = out + B * OUT + B + B * HS;          // 65408
    float* et_new     = hebb_new + (size_t)B * HS * HS;      // +32,000,000
    float* pw_new     = et_new + (size_t)B * HS * HS;

    float* hactiv = (float*)d_ws;            // [B*HS]
    float* DAout  = hactiv + B * HS;         // [B]

    // Phase 1: recurrent matvec + tanh (reads pw once — warms L3 for phase 3)
    k_hactiv<<<B * (HS / 4), 256, 0, stream>>>(
        inputs, hidden, pw, i2h_w, i2h_b, w, alpha, hactiv, hidden_new);

    // Phase 2: output heads + DA modulation
    k_heads<<<B, 256, 0, stream>>>(
        hactiv, h2o_w, h2o_b, h2v_w, h2v_b, h2DA_w, h2DA_b,
        activout, valueout, DAout);

    // Phase 3: streaming trace update, grid-stride per batch
    k_update<<<dim3(32, B), 256, 0, stream>>>(
        (const f4*)hebb, (const f4*)et, (const f4*)pw,
        hactiv, hidden, DAout, etaet,
        (f4*)hebb_new, (f4*)et_new, (f4*)pw_new);
}